// Round 6
// baseline (250.512 us; speedup 1.0000x reference)
//
#include <hip/hip_runtime.h>
#include <math.h>

#define N_NODES 50000
#define SLICE_SZ 6250          // N_NODES / 8 XCDs

__device__ __forceinline__ void fma4(float4& a, float w, const float4& v) {
    a.x += w * v.x; a.y += w * v.y; a.z += w * v.z; a.w += w * v.w;
}

// ---------------- degree histogram + per-edge rank ----------------
// rank[i] = arrival order of edge i at its dst -> later fill needs NO atomics.
__global__ void count_kernel(const int* __restrict__ dst, int E,
                             int* __restrict__ counts, int* __restrict__ rank) {
    int i = blockIdx.x * blockDim.x + threadIdx.x;
    if (i < E) rank[i] = atomicAdd(&counts[dst[i]], 1);
}

// ---------------- block-level exclusive scan ----------------
__global__ void scan_block_kernel(const int* __restrict__ in, int n,
                                  int* __restrict__ outEx, int* __restrict__ blocksum) {
    __shared__ int s[256];
    int t = threadIdx.x, i = blockIdx.x * 256 + t;
    int v = (i < n) ? in[i] : 0;
    s[t] = v;
    __syncthreads();
    for (int off = 1; off < 256; off <<= 1) {
        int x = (t >= off) ? s[t - off] : 0;
        __syncthreads();
        s[t] += x;
        __syncthreads();
    }
    if (i < n) outEx[i] = s[t] - v;
    if (t == 255 && blocksum) blocksum[blockIdx.x] = s[255];
}

__global__ void finalize_kernel(const int* __restrict__ counts, const int* __restrict__ blocksum,
                                int n, int E, int* __restrict__ row_ptr,
                                float* __restrict__ dinv) {
    int i = blockIdx.x * blockDim.x + threadIdx.x;
    if (i < n) {
        row_ptr[i] += blocksum[i >> 8];
        dinv[i] = rsqrtf((float)(counts[i] + 1));   // +1 self-loop
        if (i == 0) row_ptr[n] = E;
    }
}

// ---------------- XCD-sliced, atomic-free CSR fill ----------------
__global__ void fill2_kernel(const int* __restrict__ src, const int* __restrict__ dst,
                             const int* __restrict__ rank, int E,
                             const int* __restrict__ row_ptr, const float* __restrict__ dinv,
                             int2* __restrict__ edges) {
    const int slice = blockIdx.x & 7;
    const int chunk = blockIdx.x >> 3;
    const int CS = (((E + 255) >> 8) + 3) & ~3;      // chunk size, multiple of 4
    const int lo = chunk * CS;
    const int hi = min(E, lo + CS);
    const int slo = slice * SLICE_SZ, shi = slo + SLICE_SZ;
    if (lo >= E) return;
    const int quad_end = lo + ((hi - lo) & ~3);
    for (int i = lo + threadIdx.x * 4; i + 3 < quad_end + 4 && i + 3 < hi + 4 && i < quad_end; i += 1024) {
        int4 d4 = *(const int4*)&dst[i];
        #pragma unroll
        for (int k = 0; k < 4; ++k) {
            int d = (&d4.x)[k];
            if (d >= slo && d < shi) {
                int s = src[i + k];
                int p = row_ptr[d] + rank[i + k];
                edges[p] = make_int2(s, __float_as_int(dinv[s] * dinv[d]));
            }
        }
    }
    for (int i = quad_end + threadIdx.x; i < hi; i += 256) {   // scalar tail
        int d = dst[i];
        if (d >= slo && d < shi) {
            int s = src[i];
            int p = row_ptr[d] + rank[i];
            edges[p] = make_int2(s, __float_as_int(dinv[s] * dinv[d]));
        }
    }
}

// ---------------- fp32 GEMM: C[n,DOUT] = A[n,DIN] @ W[DIN,DOUT] ----------------
template<int DIN, int DOUT, int BM, int KC>
__global__ __launch_bounds__(256, 2) void gemm_kernel(const float* __restrict__ A,
                                                      const float* __restrict__ W,
                                                      float* __restrict__ C, int n) {
    constexpr int NCG = DOUT / 4;
    constexpr int NRG = BM / 4;
    static_assert(NCG * NRG == 256, "thread mapping");
    constexpr int KG = KC / 4;
    constexpr int RSTEP = 256 / KG;
    __shared__ __align__(16) float ws[DIN * DOUT];
    __shared__ __align__(16) float xs[KC][BM + 4];
    const int t = threadIdx.x;
    for (int i = 4 * t; i < DIN * DOUT; i += 1024)
        *(float4*)&ws[i] = *(const float4*)&W[i];
    const int rowbase = blockIdx.x * BM;
    const int r0 = (t / NCG) * 4;
    const int c0 = (t % NCG) * 4;
    const int lk = (t % KG) * 4;
    const int lr = t / KG;
    float acc[4][4] = {};
    for (int kc = 0; kc < DIN; kc += KC) {
        __syncthreads();
        #pragma unroll
        for (int r = lr; r < BM; r += RSTEP) {
            int row = rowbase + r;
            if (row >= n) row = n - 1;
            float4 v = *(const float4*)&A[(size_t)row * DIN + kc + lk];
            xs[lk + 0][r] = v.x; xs[lk + 1][r] = v.y;
            xs[lk + 2][r] = v.z; xs[lk + 3][r] = v.w;
        }
        __syncthreads();
        #pragma unroll 8
        for (int k = 0; k < KC; ++k) {
            float ar[4], wr[4];
            *(float4*)ar = *(const float4*)&xs[k][r0];
            *(float4*)wr = *(const float4*)&ws[(kc + k) * DOUT + c0];
            #pragma unroll
            for (int i = 0; i < 4; ++i)
                #pragma unroll
                for (int j = 0; j < 4; ++j)
                    acc[i][j] += ar[i] * wr[j];
        }
    }
    #pragma unroll
    for (int i = 0; i < 4; ++i) {
        int row = rowbase + r0 + i;
        if (row < n) {
            float4 v = make_float4(acc[i][0], acc[i][1], acc[i][2], acc[i][3]);
            *(float4*)&C[(size_t)row * DOUT + c0] = v;
        }
    }
}

// ---------------- layer-1 gather (vectorized, 4-deep per way) + fused GEMM2 ----------------
// Wave per node. Lanes = 16 feature-groups (float4) x 4 edge-ways.
// 4-deep unroll per way: 16 independent XW float4 gathers in flight per wave
// (round-5's 2-deep chain was latency-bound: VALUBusy 29%, HBM 19%).
__global__ __launch_bounds__(256) void gather64_fuse_kernel(
        const float* __restrict__ XW, const int* __restrict__ row_ptr,
        const int2* __restrict__ edges, const float* __restrict__ dinv,
        const float* __restrict__ b1, const float* __restrict__ W2,
        float* __restrict__ out, int n) {
    __shared__ float ws2R[64 * 33];
    const int t = threadIdx.x;
    for (int i = t; i < 64 * 32; i += 256) {
        int f = i >> 5, j = i & 31;
        ws2R[f * 33 + (((j & 7) << 2) | (j >> 3))] = W2[i];
    }
    __syncthreads();
    const int node = blockIdx.x * 4 + (t >> 6);
    if (node >= n) return;
    const int lane = t & 63;
    const int fg = lane & 15, way = lane >> 4;
    const float4* __restrict__ XW4 = (const float4*)XW;
    float4 acc = make_float4(0.f, 0.f, 0.f, 0.f);
    if (way == 0) {
        float dv = dinv[node];
        float4 v = XW4[(size_t)node * 16 + fg];
        float s2 = dv * dv;
        acc.x = s2 * v.x; acc.y = s2 * v.y; acc.z = s2 * v.z; acc.w = s2 * v.w;
    }
    int e = row_ptr[node] + way;
    const int end = row_ptr[node + 1];
    // 4 independent edges per way per iteration (edges for this way are e, e+4, e+8, ...)
    for (; e + 12 < end; e += 16) {
        int2 p0 = edges[e], p1 = edges[e + 4], p2 = edges[e + 8], p3 = edges[e + 12];
        float4 v0 = XW4[(size_t)p0.x * 16 + fg];
        float4 v1 = XW4[(size_t)p1.x * 16 + fg];
        float4 v2 = XW4[(size_t)p2.x * 16 + fg];
        float4 v3 = XW4[(size_t)p3.x * 16 + fg];
        fma4(acc, __int_as_float(p0.y), v0);
        fma4(acc, __int_as_float(p1.y), v1);
        fma4(acc, __int_as_float(p2.y), v2);
        fma4(acc, __int_as_float(p3.y), v3);
    }
    if (e + 4 < end) {                     // 2-deep mop-up
        int2 p0 = edges[e], p1 = edges[e + 4];
        float4 v0 = XW4[(size_t)p0.x * 16 + fg];
        float4 v1 = XW4[(size_t)p1.x * 16 + fg];
        fma4(acc, __int_as_float(p0.y), v0);
        fma4(acc, __int_as_float(p1.y), v1);
        e += 8;
    }
    for (; e < end; e += 4) {
        int2 p = edges[e];
        fma4(acc, __int_as_float(p.y), XW4[(size_t)p.x * 16 + fg]);
    }
    // reduce across the 4 ways (lane bits 4,5)
    #pragma unroll
    for (int m = 16; m <= 32; m <<= 1) {
        acc.x += __shfl_xor(acc.x, m, 64);
        acc.y += __shfl_xor(acc.y, m, 64);
        acc.z += __shfl_xor(acc.z, m, 64);
        acc.w += __shfl_xor(acc.w, m, 64);
    }
    float4 b = ((const float4*)b1)[fg];
    float4 h;
    h.x = fmaxf(acc.x + b.x, 0.f);
    h.y = fmaxf(acc.y + b.y, 0.f);
    h.z = fmaxf(acc.z + b.z, 0.f);
    h.w = fmaxf(acc.w + b.w, 0.f);
    // fused GEMM2: lane computes partials for cols j = way*8 + s over its 4 features
    const int rbase = fg * 132;          // (4*fg)*33
    float py[8];
    #pragma unroll
    for (int s = 0; s < 8; ++s) {
        int idx = rbase + 4 * s + way;
        py[s] = h.x * ws2R[idx]
              + h.y * ws2R[idx + 33]
              + h.z * ws2R[idx + 66]
              + h.w * ws2R[idx + 99];
    }
    #pragma unroll
    for (int m = 1; m <= 8; m <<= 1) {
        #pragma unroll
        for (int s = 0; s < 8; ++s) py[s] += __shfl_xor(py[s], m, 64);
    }
    if (fg == 0) {
        float4* o = (float4*)&out[(size_t)node * 32 + way * 8];
        o[0] = make_float4(py[0], py[1], py[2], py[3]);
        o[1] = make_float4(py[4], py[5], py[6], py[7]);
    }
}

// ---------------- layer-2 gather (vectorized) + attention epilogue ----------------
// Wave per node. Lanes = 8 feature-groups (float4 over 32 cols) x 8 edge-ways:
// unroll 2 -> 16 independent gathers in flight (already MLP-saturated).
__global__ __launch_bounds__(256) void gather32_final_kernel(
        const float* __restrict__ XW, const int* __restrict__ row_ptr,
        const int2* __restrict__ edges, const float* __restrict__ dinv,
        const float* __restrict__ b2, const float* __restrict__ aw,
        const float* __restrict__ ab, float* __restrict__ out, int n) {
    const int t = threadIdx.x;
    const int node = blockIdx.x * 4 + (t >> 6);
    if (node >= n) return;
    const int lane = t & 63;
    const int fg = lane & 7, way = lane >> 3;
    const float4* __restrict__ XW4 = (const float4*)XW;
    float4 acc = make_float4(0.f, 0.f, 0.f, 0.f);
    if (way == 0) {
        float dv = dinv[node];
        float4 v = XW4[(size_t)node * 8 + fg];
        float s2 = dv * dv;
        acc.x = s2 * v.x; acc.y = s2 * v.y; acc.z = s2 * v.z; acc.w = s2 * v.w;
    }
    int e = row_ptr[node] + way;
    const int end = row_ptr[node + 1];
    for (; e + 8 < end; e += 16) {
        int2 p0 = edges[e], p1 = edges[e + 8];
        float4 v0 = XW4[(size_t)p0.x * 8 + fg];
        float4 v1 = XW4[(size_t)p1.x * 8 + fg];
        fma4(acc, __int_as_float(p0.y), v0);
        fma4(acc, __int_as_float(p1.y), v1);
    }
    for (; e < end; e += 8) {
        int2 p = edges[e];
        fma4(acc, __int_as_float(p.y), XW4[(size_t)p.x * 8 + fg]);
    }
    #pragma unroll
    for (int m = 8; m <= 32; m <<= 1) {
        acc.x += __shfl_xor(acc.x, m, 64);
        acc.y += __shfl_xor(acc.y, m, 64);
        acc.z += __shfl_xor(acc.z, m, 64);
        acc.w += __shfl_xor(acc.w, m, 64);
    }
    float4 b = ((const float4*)b2)[fg];
    float4 h;
    h.x = fmaxf(acc.x + b.x, 0.f);
    h.y = fmaxf(acc.y + b.y, 0.f);
    h.z = fmaxf(acc.z + b.z, 0.f);
    h.w = fmaxf(acc.w + b.w, 0.f);
    float4 a4 = ((const float4*)aw)[fg];
    float sca = h.x * a4.x + h.y * a4.y + h.z * a4.z + h.w * a4.w;
    sca += __shfl_xor(sca, 1, 64);
    sca += __shfl_xor(sca, 2, 64);
    sca += __shfl_xor(sca, 4, 64);
    float attn = 1.f / (1.f + __expf(-(sca + ab[0])));
    if (way == 0) {
        float4 r = make_float4(h.x * attn, h.y * attn, h.z * attn, h.w * attn);
        ((float4*)&out[(size_t)node * 32])[fg] = r;
    }
}

extern "C" void kernel_launch(void* const* d_in, const int* in_sizes, int n_in,
                              void* d_out, int out_size, void* d_ws, size_t ws_size,
                              hipStream_t stream) {
    const float* x  = (const float*)d_in[0];
    const int*   ei = (const int*)d_in[1];
    const float* W1 = (const float*)d_in[2];
    const float* b1 = (const float*)d_in[3];
    const float* W2 = (const float*)d_in[4];
    const float* b2 = (const float*)d_in[5];
    const float* aw = (const float*)d_in[6];
    const float* ab = (const float*)d_in[7];
    float* out = (float*)d_out;

    const int n = N_NODES;
    const int E = in_sizes[1] / 2;
    const int* src = ei;
    const int* dst = ei + E;

    char* w = (char*)d_ws;
    auto alloc = [&](size_t bytes) { char* p = w; w += (bytes + 255) & ~(size_t)255; return p; };
    int*   counts   = (int*)  alloc((size_t)n * 4);
    int*   row_ptr  = (int*)  alloc((size_t)(n + 1) * 4);
    int*   rank     = (int*)  alloc((size_t)E * 4);
    int*   blocksum = (int*)  alloc(1024);
    float* dinv     = (float*)alloc((size_t)n * 4);
    int2*  edges    = (int2*) alloc((size_t)E * 8);
    float* bufA     = (float*)alloc((size_t)n * 64 * 4);   // XW1
    float* bufB     = (float*)alloc((size_t)n * 32 * 4);   // XW2 (= h1 @ W2)

    const int nb = (n + 255) / 256;

    hipMemsetAsync(counts, 0, (size_t)n * 4, stream);
    count_kernel<<<(E + 255) / 256, 256, 0, stream>>>(dst, E, counts, rank);
    scan_block_kernel<<<nb, 256, 0, stream>>>(counts, n, row_ptr, blocksum);
    scan_block_kernel<<<1, 256, 0, stream>>>(blocksum, nb, blocksum, nullptr);
    finalize_kernel<<<nb, 256, 0, stream>>>(counts, blocksum, n, E, row_ptr, dinv);
    fill2_kernel<<<256 * 8, 256, 0, stream>>>(src, dst, rank, E, row_ptr, dinv, edges);

    gemm_kernel<128, 64, 64, 32><<<(n + 63) / 64, 256, 0, stream>>>(x, W1, bufA, n);
    gather64_fuse_kernel<<<(n + 3) / 4, 256, 0, stream>>>(
        bufA, row_ptr, edges, dinv, b1, W2, bufB, n);
    gather32_final_kernel<<<(n + 3) / 4, 256, 0, stream>>>(
        bufB, row_ptr, edges, dinv, b2, aw, ab, out, n);
}

// Round 7
// 247.793 us; speedup vs baseline: 1.0110x; 1.0110x over previous
//
#include <hip/hip_runtime.h>
#include <hip/hip_fp16.h>
#include <math.h>

#define N_NODES 50000
#define SLICE_SZ 6250          // N_NODES / 8 XCDs

__device__ __forceinline__ void fma4(float4& a, float w, const float4& v) {
    a.x += w * v.x; a.y += w * v.y; a.z += w * v.z; a.w += w * v.w;
}

struct h2x2 { __half2 a, b; };   // 8 bytes = 4 halves

// ---------------- degree histogram + per-edge rank ----------------
__global__ void count_kernel(const int* __restrict__ dst, int E,
                             int* __restrict__ counts, int* __restrict__ rank) {
    int i = blockIdx.x * blockDim.x + threadIdx.x;
    if (i < E) rank[i] = atomicAdd(&counts[dst[i]], 1);
}

// ---------------- block-level exclusive scan ----------------
__global__ void scan_block_kernel(const int* __restrict__ in, int n,
                                  int* __restrict__ outEx, int* __restrict__ blocksum) {
    __shared__ int s[256];
    int t = threadIdx.x, i = blockIdx.x * 256 + t;
    int v = (i < n) ? in[i] : 0;
    s[t] = v;
    __syncthreads();
    for (int off = 1; off < 256; off <<= 1) {
        int x = (t >= off) ? s[t - off] : 0;
        __syncthreads();
        s[t] += x;
        __syncthreads();
    }
    if (i < n) outEx[i] = s[t] - v;
    if (t == 255 && blocksum) blocksum[blockIdx.x] = s[255];
}

__global__ void finalize_kernel(const int* __restrict__ counts, const int* __restrict__ blocksum,
                                int n, int E, int* __restrict__ row_ptr,
                                float* __restrict__ dinv) {
    int i = blockIdx.x * blockDim.x + threadIdx.x;
    if (i < n) {
        row_ptr[i] += blocksum[i >> 8];
        dinv[i] = rsqrtf((float)(counts[i] + 1));   // +1 self-loop
        if (i == 0) row_ptr[n] = E;
    }
}

// ---------------- XCD-sliced, atomic-free CSR fill ----------------
__global__ void fill2_kernel(const int* __restrict__ src, const int* __restrict__ dst,
                             const int* __restrict__ rank, int E,
                             const int* __restrict__ row_ptr, const float* __restrict__ dinv,
                             int2* __restrict__ edges) {
    const int slice = blockIdx.x & 7;
    const int chunk = blockIdx.x >> 3;
    const int CS = (((E + 255) >> 8) + 3) & ~3;      // chunk size, multiple of 4
    const int lo = chunk * CS;
    const int hi = min(E, lo + CS);
    const int slo = slice * SLICE_SZ, shi = slo + SLICE_SZ;
    if (lo >= E) return;
    const int quad_end = lo + ((hi - lo) & ~3);
    for (int i = lo + threadIdx.x * 4; i + 3 < quad_end + 4 && i + 3 < hi + 4 && i < quad_end; i += 1024) {
        int4 d4 = *(const int4*)&dst[i];
        #pragma unroll
        for (int k = 0; k < 4; ++k) {
            int d = (&d4.x)[k];
            if (d >= slo && d < shi) {
                int s = src[i + k];
                int p = row_ptr[d] + rank[i + k];
                edges[p] = make_int2(s, __float_as_int(dinv[s] * dinv[d]));
            }
        }
    }
    for (int i = quad_end + threadIdx.x; i < hi; i += 256) {   // scalar tail
        int d = dst[i];
        if (d >= slo && d < shi) {
            int s = src[i];
            int p = row_ptr[d] + rank[i];
            edges[p] = make_int2(s, __float_as_int(dinv[s] * dinv[d]));
        }
    }
}

// ---------------- fp32 GEMM: C[n,DOUT] = A[n,DIN] @ W[DIN,DOUT] ----------------
// HOUT: emit fp16 (halves the table bytes the downstream gather must pull
// through 8 private L2s -- the measured compulsory-miss bound).
template<int DIN, int DOUT, int BM, int KC, bool HOUT>
__global__ __launch_bounds__(256, 2) void gemm_kernel(const float* __restrict__ A,
                                                      const float* __restrict__ W,
                                                      void* __restrict__ Cv, int n) {
    constexpr int NCG = DOUT / 4;
    constexpr int NRG = BM / 4;
    static_assert(NCG * NRG == 256, "thread mapping");
    constexpr int KG = KC / 4;
    constexpr int RSTEP = 256 / KG;
    __shared__ __align__(16) float ws[DIN * DOUT];
    __shared__ __align__(16) float xs[KC][BM + 4];
    const int t = threadIdx.x;
    for (int i = 4 * t; i < DIN * DOUT; i += 1024)
        *(float4*)&ws[i] = *(const float4*)&W[i];
    const int rowbase = blockIdx.x * BM;
    const int r0 = (t / NCG) * 4;
    const int c0 = (t % NCG) * 4;
    const int lk = (t % KG) * 4;
    const int lr = t / KG;
    float acc[4][4] = {};
    for (int kc = 0; kc < DIN; kc += KC) {
        __syncthreads();
        #pragma unroll
        for (int r = lr; r < BM; r += RSTEP) {
            int row = rowbase + r;
            if (row >= n) row = n - 1;
            float4 v = *(const float4*)&A[(size_t)row * DIN + kc + lk];
            xs[lk + 0][r] = v.x; xs[lk + 1][r] = v.y;
            xs[lk + 2][r] = v.z; xs[lk + 3][r] = v.w;
        }
        __syncthreads();
        #pragma unroll 8
        for (int k = 0; k < KC; ++k) {
            float ar[4], wr[4];
            *(float4*)ar = *(const float4*)&xs[k][r0];
            *(float4*)wr = *(const float4*)&ws[(kc + k) * DOUT + c0];
            #pragma unroll
            for (int i = 0; i < 4; ++i)
                #pragma unroll
                for (int j = 0; j < 4; ++j)
                    acc[i][j] += ar[i] * wr[j];
        }
    }
    #pragma unroll
    for (int i = 0; i < 4; ++i) {
        int row = rowbase + r0 + i;
        if (row < n) {
            if constexpr (HOUT) {
                union { uint2 u; __half2 h[2]; } pk;
                pk.h[0] = __floats2half2_rn(acc[i][0], acc[i][1]);
                pk.h[1] = __floats2half2_rn(acc[i][2], acc[i][3]);
                *(uint2*)((__half*)Cv + (size_t)row * DOUT + c0) = pk.u;
            } else {
                float4 v = make_float4(acc[i][0], acc[i][1], acc[i][2], acc[i][3]);
                *(float4*)&((float*)Cv)[(size_t)row * DOUT + c0] = v;
            }
        }
    }
}

// ---------------- layer-1 gather (fp16 table) + fused GEMM2 ----------------
// Wave per node. Lanes = 16 feature-groups (4 halves each, 8B/lane) x 4 ways.
// fp16 halves the compulsory L2-miss traffic (83 -> ~46 MB); accumulate fp32.
__global__ __launch_bounds__(256) void gather64_fuse_kernel(
        const __half* __restrict__ XWh, const int* __restrict__ row_ptr,
        const int2* __restrict__ edges, const float* __restrict__ dinv,
        const float* __restrict__ b1, const float* __restrict__ W2,
        float* __restrict__ out, int n) {
    __shared__ float ws2R[64 * 33];
    const int t = threadIdx.x;
    for (int i = t; i < 64 * 32; i += 256) {
        int f = i >> 5, j = i & 31;
        ws2R[f * 33 + (((j & 7) << 2) | (j >> 3))] = W2[i];
    }
    __syncthreads();
    const int node = blockIdx.x * 4 + (t >> 6);
    if (node >= n) return;
    const int lane = t & 63;
    const int fg = lane & 15, way = lane >> 4;
    const h2x2* __restrict__ XW4 = (const h2x2*)XWh;   // 16 units of 4 halves per row
    float4 acc = make_float4(0.f, 0.f, 0.f, 0.f);
    if (way == 0) {
        float dv = dinv[node];
        h2x2 r = XW4[(size_t)node * 16 + fg];
        float2 f0 = __half22float2(r.a), f1 = __half22float2(r.b);
        float s2 = dv * dv;
        acc.x = s2 * f0.x; acc.y = s2 * f0.y; acc.z = s2 * f1.x; acc.w = s2 * f1.y;
    }
    int e = row_ptr[node] + way;
    const int end = row_ptr[node + 1];
    for (; e + 4 < end; e += 8) {          // 2-deep per way = 8 rows in flight
        int2 p0 = edges[e], p1 = edges[e + 4];
        h2x2 r0 = XW4[(size_t)p0.x * 16 + fg];
        h2x2 r1 = XW4[(size_t)p1.x * 16 + fg];
        float w0 = __int_as_float(p0.y), w1 = __int_as_float(p1.y);
        float2 a0 = __half22float2(r0.a), b0 = __half22float2(r0.b);
        float2 a1 = __half22float2(r1.a), b1v = __half22float2(r1.b);
        acc.x += w0 * a0.x; acc.y += w0 * a0.y; acc.z += w0 * b0.x; acc.w += w0 * b0.y;
        acc.x += w1 * a1.x; acc.y += w1 * a1.y; acc.z += w1 * b1v.x; acc.w += w1 * b1v.y;
    }
    for (; e < end; e += 4) {
        int2 p = edges[e];
        h2x2 r = XW4[(size_t)p.x * 16 + fg];
        float w0 = __int_as_float(p.y);
        float2 a0 = __half22float2(r.a), b0 = __half22float2(r.b);
        acc.x += w0 * a0.x; acc.y += w0 * a0.y; acc.z += w0 * b0.x; acc.w += w0 * b0.y;
    }
    // reduce across the 4 ways (lane bits 4,5)
    #pragma unroll
    for (int m = 16; m <= 32; m <<= 1) {
        acc.x += __shfl_xor(acc.x, m, 64);
        acc.y += __shfl_xor(acc.y, m, 64);
        acc.z += __shfl_xor(acc.z, m, 64);
        acc.w += __shfl_xor(acc.w, m, 64);
    }
    float4 b = ((const float4*)b1)[fg];
    float4 h;
    h.x = fmaxf(acc.x + b.x, 0.f);
    h.y = fmaxf(acc.y + b.y, 0.f);
    h.z = fmaxf(acc.z + b.z, 0.f);
    h.w = fmaxf(acc.w + b.w, 0.f);
    // fused GEMM2: lane computes partials for cols j = way*8 + s over its 4 features
    const int rbase = fg * 132;          // (4*fg)*33
    float py[8];
    #pragma unroll
    for (int s = 0; s < 8; ++s) {
        int idx = rbase + 4 * s + way;
        py[s] = h.x * ws2R[idx]
              + h.y * ws2R[idx + 33]
              + h.z * ws2R[idx + 66]
              + h.w * ws2R[idx + 99];
    }
    #pragma unroll
    for (int m = 1; m <= 8; m <<= 1) {
        #pragma unroll
        for (int s = 0; s < 8; ++s) py[s] += __shfl_xor(py[s], m, 64);
    }
    if (fg == 0) {
        float4* o = (float4*)&out[(size_t)node * 32 + way * 8];
        o[0] = make_float4(py[0], py[1], py[2], py[3]);
        o[1] = make_float4(py[4], py[5], py[6], py[7]);
    }
}

// ---------------- layer-2 gather (fp32) + attention epilogue ----------------
__global__ __launch_bounds__(256) void gather32_final_kernel(
        const float* __restrict__ XW, const int* __restrict__ row_ptr,
        const int2* __restrict__ edges, const float* __restrict__ dinv,
        const float* __restrict__ b2, const float* __restrict__ aw,
        const float* __restrict__ ab, float* __restrict__ out, int n) {
    const int t = threadIdx.x;
    const int node = blockIdx.x * 4 + (t >> 6);
    if (node >= n) return;
    const int lane = t & 63;
    const int fg = lane & 7, way = lane >> 3;
    const float4* __restrict__ XW4 = (const float4*)XW;
    float4 acc = make_float4(0.f, 0.f, 0.f, 0.f);
    if (way == 0) {
        float dv = dinv[node];
        float4 v = XW4[(size_t)node * 8 + fg];
        float s2 = dv * dv;
        acc.x = s2 * v.x; acc.y = s2 * v.y; acc.z = s2 * v.z; acc.w = s2 * v.w;
    }
    int e = row_ptr[node] + way;
    const int end = row_ptr[node + 1];
    for (; e + 8 < end; e += 16) {
        int2 p0 = edges[e], p1 = edges[e + 8];
        float4 v0 = XW4[(size_t)p0.x * 8 + fg];
        float4 v1 = XW4[(size_t)p1.x * 8 + fg];
        fma4(acc, __int_as_float(p0.y), v0);
        fma4(acc, __int_as_float(p1.y), v1);
    }
    for (; e < end; e += 8) {
        int2 p = edges[e];
        fma4(acc, __int_as_float(p.y), XW4[(size_t)p.x * 8 + fg]);
    }
    #pragma unroll
    for (int m = 8; m <= 32; m <<= 1) {
        acc.x += __shfl_xor(acc.x, m, 64);
        acc.y += __shfl_xor(acc.y, m, 64);
        acc.z += __shfl_xor(acc.z, m, 64);
        acc.w += __shfl_xor(acc.w, m, 64);
    }
    float4 b = ((const float4*)b2)[fg];
    float4 h;
    h.x = fmaxf(acc.x + b.x, 0.f);
    h.y = fmaxf(acc.y + b.y, 0.f);
    h.z = fmaxf(acc.z + b.z, 0.f);
    h.w = fmaxf(acc.w + b.w, 0.f);
    float4 a4 = ((const float4*)aw)[fg];
    float sca = h.x * a4.x + h.y * a4.y + h.z * a4.z + h.w * a4.w;
    sca += __shfl_xor(sca, 1, 64);
    sca += __shfl_xor(sca, 2, 64);
    sca += __shfl_xor(sca, 4, 64);
    float attn = 1.f / (1.f + __expf(-(sca + ab[0])));
    if (way == 0) {
        float4 r = make_float4(h.x * attn, h.y * attn, h.z * attn, h.w * attn);
        ((float4*)&out[(size_t)node * 32])[fg] = r;
    }
}

extern "C" void kernel_launch(void* const* d_in, const int* in_sizes, int n_in,
                              void* d_out, int out_size, void* d_ws, size_t ws_size,
                              hipStream_t stream) {
    const float* x  = (const float*)d_in[0];
    const int*   ei = (const int*)d_in[1];
    const float* W1 = (const float*)d_in[2];
    const float* b1 = (const float*)d_in[3];
    const float* W2 = (const float*)d_in[4];
    const float* b2 = (const float*)d_in[5];
    const float* aw = (const float*)d_in[6];
    const float* ab = (const float*)d_in[7];
    float* out = (float*)d_out;

    const int n = N_NODES;
    const int E = in_sizes[1] / 2;
    const int* src = ei;
    const int* dst = ei + E;

    char* w = (char*)d_ws;
    auto alloc = [&](size_t bytes) { char* p = w; w += (bytes + 255) & ~(size_t)255; return p; };
    int*    counts   = (int*)   alloc((size_t)n * 4);
    int*    row_ptr  = (int*)   alloc((size_t)(n + 1) * 4);
    int*    rank     = (int*)   alloc((size_t)E * 4);
    int*    blocksum = (int*)   alloc(1024);
    float*  dinv     = (float*) alloc((size_t)n * 4);
    int2*   edges    = (int2*)  alloc((size_t)E * 8);
    __half* bufAh    = (__half*)alloc((size_t)n * 64 * 2);   // XW1 (fp16 table)
    float*  bufB     = (float*) alloc((size_t)n * 32 * 4);   // XW2 (= h1 @ W2, fp32)

    const int nb = (n + 255) / 256;

    hipMemsetAsync(counts, 0, (size_t)n * 4, stream);
    count_kernel<<<(E + 255) / 256, 256, 0, stream>>>(dst, E, counts, rank);
    scan_block_kernel<<<nb, 256, 0, stream>>>(counts, n, row_ptr, blocksum);
    scan_block_kernel<<<1, 256, 0, stream>>>(blocksum, nb, blocksum, nullptr);
    finalize_kernel<<<nb, 256, 0, stream>>>(counts, blocksum, n, E, row_ptr, dinv);
    fill2_kernel<<<256 * 8, 256, 0, stream>>>(src, dst, rank, E, row_ptr, dinv, edges);

    gemm_kernel<128, 64, 64, 32, true><<<(n + 63) / 64, 256, 0, stream>>>(x, W1, bufAh, n);
    gather64_fuse_kernel<<<(n + 3) / 4, 256, 0, stream>>>(
        bufAh, row_ptr, edges, dinv, b1, W2, bufB, n);
    gather32_final_kernel<<<(n + 3) / 4, 256, 0, stream>>>(
        bufB, row_ptr, edges, dinv, b2, aw, ab, out, n);
}

// Round 8
// 237.385 us; speedup vs baseline: 1.0553x; 1.0438x over previous
//
#include <hip/hip_runtime.h>
#include <hip/hip_fp16.h>
#include <math.h>

#define N_NODES 50000
#define SLICE_SZ 6250          // N_NODES / 8 XCDs

__device__ __forceinline__ void fma4(float4& a, float w, const float4& v) {
    a.x += w * v.x; a.y += w * v.y; a.z += w * v.z; a.w += w * v.w;
}

struct h2x2 { __half2 a, b; };   // 8 bytes = 4 halves

// ---------------- degree histogram + per-edge rank ----------------
__global__ void count_kernel(const int* __restrict__ dst, int E,
                             int* __restrict__ counts, int* __restrict__ rank) {
    int i = blockIdx.x * blockDim.x + threadIdx.x;
    if (i < E) rank[i] = atomicAdd(&counts[dst[i]], 1);
}

// ---------------- block-level exclusive scan ----------------
__global__ void scan_block_kernel(const int* __restrict__ in, int n,
                                  int* __restrict__ outEx, int* __restrict__ blocksum) {
    __shared__ int s[256];
    int t = threadIdx.x, i = blockIdx.x * 256 + t;
    int v = (i < n) ? in[i] : 0;
    s[t] = v;
    __syncthreads();
    for (int off = 1; off < 256; off <<= 1) {
        int x = (t >= off) ? s[t - off] : 0;
        __syncthreads();
        s[t] += x;
        __syncthreads();
    }
    if (i < n) outEx[i] = s[t] - v;
    if (t == 255 && blocksum) blocksum[blockIdx.x] = s[255];
}

__global__ void finalize_kernel(const int* __restrict__ counts, const int* __restrict__ blocksum,
                                int n, int E, int* __restrict__ row_ptr,
                                float* __restrict__ dinv) {
    int i = blockIdx.x * blockDim.x + threadIdx.x;
    if (i < n) {
        row_ptr[i] += blocksum[i >> 8];
        dinv[i] = rsqrtf((float)(counts[i] + 1));   // +1 self-loop
        if (i == 0) row_ptr[n] = E;
    }
}

// ---------------- XCD-sliced, atomic-free CSR fill ----------------
__global__ void fill2_kernel(const int* __restrict__ src, const int* __restrict__ dst,
                             const int* __restrict__ rank, int E,
                             const int* __restrict__ row_ptr, const float* __restrict__ dinv,
                             int2* __restrict__ edges) {
    const int slice = blockIdx.x & 7;
    const int chunk = blockIdx.x >> 3;
    const int CS = (((E + 255) >> 8) + 3) & ~3;      // chunk size, multiple of 4
    const int lo = chunk * CS;
    const int hi = min(E, lo + CS);
    const int slo = slice * SLICE_SZ, shi = slo + SLICE_SZ;
    if (lo >= E) return;
    const int quad_end = lo + ((hi - lo) & ~3);
    for (int i = lo + threadIdx.x * 4; i + 3 < quad_end + 4 && i + 3 < hi + 4 && i < quad_end; i += 1024) {
        int4 d4 = *(const int4*)&dst[i];
        #pragma unroll
        for (int k = 0; k < 4; ++k) {
            int d = (&d4.x)[k];
            if (d >= slo && d < shi) {
                int s = src[i + k];
                int p = row_ptr[d] + rank[i + k];
                edges[p] = make_int2(s, __float_as_int(dinv[s] * dinv[d]));
            }
        }
    }
    for (int i = quad_end + threadIdx.x; i < hi; i += 256) {   // scalar tail
        int d = dst[i];
        if (d >= slo && d < shi) {
            int s = src[i];
            int p = row_ptr[d] + rank[i];
            edges[p] = make_int2(s, __float_as_int(dinv[s] * dinv[d]));
        }
    }
}

// ---------------- fp32 GEMM: C[n,DOUT] = A[n,DIN] @ W[DIN,DOUT] ----------------
template<int DIN, int DOUT, int BM, int KC, bool HOUT>
__global__ __launch_bounds__(256, 2) void gemm_kernel(const float* __restrict__ A,
                                                      const float* __restrict__ W,
                                                      void* __restrict__ Cv, int n) {
    constexpr int NCG = DOUT / 4;
    constexpr int NRG = BM / 4;
    static_assert(NCG * NRG == 256, "thread mapping");
    constexpr int KG = KC / 4;
    constexpr int RSTEP = 256 / KG;
    __shared__ __align__(16) float ws[DIN * DOUT];
    __shared__ __align__(16) float xs[KC][BM + 4];
    const int t = threadIdx.x;
    for (int i = 4 * t; i < DIN * DOUT; i += 1024)
        *(float4*)&ws[i] = *(const float4*)&W[i];
    const int rowbase = blockIdx.x * BM;
    const int r0 = (t / NCG) * 4;
    const int c0 = (t % NCG) * 4;
    const int lk = (t % KG) * 4;
    const int lr = t / KG;
    float acc[4][4] = {};
    for (int kc = 0; kc < DIN; kc += KC) {
        __syncthreads();
        #pragma unroll
        for (int r = lr; r < BM; r += RSTEP) {
            int row = rowbase + r;
            if (row >= n) row = n - 1;
            float4 v = *(const float4*)&A[(size_t)row * DIN + kc + lk];
            xs[lk + 0][r] = v.x; xs[lk + 1][r] = v.y;
            xs[lk + 2][r] = v.z; xs[lk + 3][r] = v.w;
        }
        __syncthreads();
        #pragma unroll 8
        for (int k = 0; k < KC; ++k) {
            float ar[4], wr[4];
            *(float4*)ar = *(const float4*)&xs[k][r0];
            *(float4*)wr = *(const float4*)&ws[(kc + k) * DOUT + c0];
            #pragma unroll
            for (int i = 0; i < 4; ++i)
                #pragma unroll
                for (int j = 0; j < 4; ++j)
                    acc[i][j] += ar[i] * wr[j];
        }
    }
    #pragma unroll
    for (int i = 0; i < 4; ++i) {
        int row = rowbase + r0 + i;
        if (row < n) {
            if constexpr (HOUT) {
                union { uint2 u; __half2 h[2]; } pk;
                pk.h[0] = __floats2half2_rn(acc[i][0], acc[i][1]);
                pk.h[1] = __floats2half2_rn(acc[i][2], acc[i][3]);
                *(uint2*)((__half*)Cv + (size_t)row * DOUT + c0) = pk.u;
            } else {
                float4 v = make_float4(acc[i][0], acc[i][1], acc[i][2], acc[i][3]);
                *(float4*)&((float*)Cv)[(size_t)row * DOUT + c0] = v;
            }
        }
    }
}

// ---------------- layer-1 gather (shfl-broadcast records) + fused GEMM2 ----------------
// Wave per node (4 nodes per wave, 16 per block). Phase A: ONE coalesced vmem
// loads all <=63 edge records into lanes (record 0 = folded self-loop).
// Phase B: records broadcast via shfl -> the gather loop has NO dependent
// loads; 4-deep unroll keeps 4 independent row-gathers in flight per way.
__global__ __launch_bounds__(256) void gather64_fuse_kernel(
        const __half* __restrict__ XWh, const int* __restrict__ row_ptr,
        const int2* __restrict__ edges, const float* __restrict__ dinv,
        const float* __restrict__ b1, const float* __restrict__ W2,
        float* __restrict__ out, int n) {
    __shared__ float ws2R[64 * 33];
    const int t = threadIdx.x;
    for (int i = t; i < 64 * 32; i += 256) {
        int f = i >> 5, j = i & 31;
        ws2R[f * 33 + (((j & 7) << 2) | (j >> 3))] = W2[i];
    }
    __syncthreads();
    const int lane = t & 63;
    const int wid = t >> 6;
    const int fg = lane & 15, way = lane >> 4;
    const h2x2* __restrict__ XW4 = (const h2x2*)XWh;
    for (int it = 0; it < 4; ++it) {
        const int node = blockIdx.x * 16 + wid * 4 + it;
        if (node >= n) break;                       // wave-uniform
        const int start = row_ptr[node];
        const int deg = row_ptr[node + 1] - start;
        const int K = deg + 1;                      // + self record
        // phase A: lane k holds record k (k=0: self)
        int2 rec;
        if (lane == 0) {
            float dv = dinv[node];
            rec = make_int2(node, __float_as_int(dv * dv));
        } else if (lane <= deg) {
            rec = edges[start + lane - 1];
        } else {
            rec = make_int2(node, 0);               // weight-0 pad
        }
        float4 acc = make_float4(0.f, 0.f, 0.f, 0.f);
        const int KP = (min(K, 64) + 3) & ~3;       // uniform per-way count
        int k = way;
        #define G64_STEP(kk)                                                   \
            { int sv = __shfl(rec.x, (kk), 64);                                \
              float wgt = __int_as_float(__shfl(rec.y, (kk), 64));             \
              h2x2 rr = XW4[(size_t)sv * 16 + fg];                             \
              float2 a0 = __half22float2(rr.a), b0 = __half22float2(rr.b);     \
              acc.x += wgt * a0.x; acc.y += wgt * a0.y;                        \
              acc.z += wgt * b0.x; acc.w += wgt * b0.y; }
        for (; k + 12 < KP; k += 16) {
            G64_STEP(k) G64_STEP(k + 4) G64_STEP(k + 8) G64_STEP(k + 12)
        }
        for (; k < KP; k += 4) G64_STEP(k)
        #undef G64_STEP
        for (int kk = 64 + way; kk < K; kk += 4) {  // deg>63: direct (never in practice)
            int2 p = edges[start + kk - 1];
            float wgt = __int_as_float(p.y);
            h2x2 rr = XW4[(size_t)p.x * 16 + fg];
            float2 a0 = __half22float2(rr.a), b0 = __half22float2(rr.b);
            acc.x += wgt * a0.x; acc.y += wgt * a0.y;
            acc.z += wgt * b0.x; acc.w += wgt * b0.y;
        }
        // reduce across the 4 ways (lane bits 4,5)
        #pragma unroll
        for (int m = 16; m <= 32; m <<= 1) {
            acc.x += __shfl_xor(acc.x, m, 64);
            acc.y += __shfl_xor(acc.y, m, 64);
            acc.z += __shfl_xor(acc.z, m, 64);
            acc.w += __shfl_xor(acc.w, m, 64);
        }
        float4 b = ((const float4*)b1)[fg];
        float4 h;
        h.x = fmaxf(acc.x + b.x, 0.f);
        h.y = fmaxf(acc.y + b.y, 0.f);
        h.z = fmaxf(acc.z + b.z, 0.f);
        h.w = fmaxf(acc.w + b.w, 0.f);
        // fused GEMM2: lane computes partials for cols j = way*8 + s
        const int rbase = fg * 132;                 // (4*fg)*33
        float py[8];
        #pragma unroll
        for (int s = 0; s < 8; ++s) {
            int idx = rbase + 4 * s + way;
            py[s] = h.x * ws2R[idx]
                  + h.y * ws2R[idx + 33]
                  + h.z * ws2R[idx + 66]
                  + h.w * ws2R[idx + 99];
        }
        #pragma unroll
        for (int m = 1; m <= 8; m <<= 1) {
            #pragma unroll
            for (int s = 0; s < 8; ++s) py[s] += __shfl_xor(py[s], m, 64);
        }
        if (fg == 0) {
            float4* o = (float4*)&out[(size_t)node * 32 + way * 8];
            o[0] = make_float4(py[0], py[1], py[2], py[3]);
            o[1] = make_float4(py[4], py[5], py[6], py[7]);
        }
    }
}

// ---------------- layer-2 gather (shfl-broadcast) + attention epilogue ----------------
// Wave per node (4 nodes/wave). Lanes = 8 fg (float4) x 8 ways.
__global__ __launch_bounds__(256) void gather32_final_kernel(
        const float* __restrict__ XW, const int* __restrict__ row_ptr,
        const int2* __restrict__ edges, const float* __restrict__ dinv,
        const float* __restrict__ b2, const float* __restrict__ aw,
        const float* __restrict__ ab, float* __restrict__ out, int n) {
    const int t = threadIdx.x;
    const int lane = t & 63;
    const int wid = t >> 6;
    const int fg = lane & 7, way = lane >> 3;
    const float4* __restrict__ XW4 = (const float4*)XW;
    for (int it = 0; it < 4; ++it) {
        const int node = blockIdx.x * 16 + wid * 4 + it;
        if (node >= n) break;
        const int start = row_ptr[node];
        const int deg = row_ptr[node + 1] - start;
        const int K = deg + 1;
        int2 rec;
        if (lane == 0) {
            float dv = dinv[node];
            rec = make_int2(node, __float_as_int(dv * dv));
        } else if (lane <= deg) {
            rec = edges[start + lane - 1];
        } else {
            rec = make_int2(node, 0);
        }
        float4 acc = make_float4(0.f, 0.f, 0.f, 0.f);
        const int KP = (min(K, 64) + 7) & ~7;
        int k = way;
        #define G32_STEP(kk)                                                   \
            { int sv = __shfl(rec.x, (kk), 64);                                \
              float wgt = __int_as_float(__shfl(rec.y, (kk), 64));             \
              float4 v = XW4[(size_t)sv * 8 + fg];                             \
              fma4(acc, wgt, v); }
        for (; k + 24 < KP; k += 32) {
            G32_STEP(k) G32_STEP(k + 8) G32_STEP(k + 16) G32_STEP(k + 24)
        }
        for (; k < KP; k += 8) G32_STEP(k)
        #undef G32_STEP
        for (int kk = 64 + way; kk < K; kk += 8) {  // deg>63: direct (never in practice)
            int2 p = edges[start + kk - 1];
            fma4(acc, __int_as_float(p.y), XW4[(size_t)p.x * 8 + fg]);
        }
        #pragma unroll
        for (int m = 8; m <= 32; m <<= 1) {
            acc.x += __shfl_xor(acc.x, m, 64);
            acc.y += __shfl_xor(acc.y, m, 64);
            acc.z += __shfl_xor(acc.z, m, 64);
            acc.w += __shfl_xor(acc.w, m, 64);
        }
        float4 b = ((const float4*)b2)[fg];
        float4 h;
        h.x = fmaxf(acc.x + b.x, 0.f);
        h.y = fmaxf(acc.y + b.y, 0.f);
        h.z = fmaxf(acc.z + b.z, 0.f);
        h.w = fmaxf(acc.w + b.w, 0.f);
        float4 a4 = ((const float4*)aw)[fg];
        float sca = h.x * a4.x + h.y * a4.y + h.z * a4.z + h.w * a4.w;
        sca += __shfl_xor(sca, 1, 64);
        sca += __shfl_xor(sca, 2, 64);
        sca += __shfl_xor(sca, 4, 64);
        float attn = 1.f / (1.f + __expf(-(sca + ab[0])));
        if (way == 0) {
            float4 r = make_float4(h.x * attn, h.y * attn, h.z * attn, h.w * attn);
            ((float4*)&out[(size_t)node * 32])[fg] = r;
        }
    }
}

extern "C" void kernel_launch(void* const* d_in, const int* in_sizes, int n_in,
                              void* d_out, int out_size, void* d_ws, size_t ws_size,
                              hipStream_t stream) {
    const float* x  = (const float*)d_in[0];
    const int*   ei = (const int*)d_in[1];
    const float* W1 = (const float*)d_in[2];
    const float* b1 = (const float*)d_in[3];
    const float* W2 = (const float*)d_in[4];
    const float* b2 = (const float*)d_in[5];
    const float* aw = (const float*)d_in[6];
    const float* ab = (const float*)d_in[7];
    float* out = (float*)d_out;

    const int n = N_NODES;
    const int E = in_sizes[1] / 2;
    const int* src = ei;
    const int* dst = ei + E;

    char* w = (char*)d_ws;
    auto alloc = [&](size_t bytes) { char* p = w; w += (bytes + 255) & ~(size_t)255; return p; };
    int*    counts   = (int*)   alloc((size_t)n * 4);
    int*    row_ptr  = (int*)   alloc((size_t)(n + 1) * 4);
    int*    rank     = (int*)   alloc((size_t)E * 4);
    int*    blocksum = (int*)   alloc(1024);
    float*  dinv     = (float*) alloc((size_t)n * 4);
    int2*   edges    = (int2*)  alloc((size_t)E * 8);
    __half* bufAh    = (__half*)alloc((size_t)n * 64 * 2);   // XW1 (fp16 table)
    float*  bufB     = (float*) alloc((size_t)n * 32 * 4);   // XW2 (fp32)

    const int nb = (n + 255) / 256;

    hipMemsetAsync(counts, 0, (size_t)n * 4, stream);
    count_kernel<<<(E + 255) / 256, 256, 0, stream>>>(dst, E, counts, rank);
    scan_block_kernel<<<nb, 256, 0, stream>>>(counts, n, row_ptr, blocksum);
    scan_block_kernel<<<1, 256, 0, stream>>>(blocksum, nb, blocksum, nullptr);
    finalize_kernel<<<nb, 256, 0, stream>>>(counts, blocksum, n, E, row_ptr, dinv);
    fill2_kernel<<<256 * 8, 256, 0, stream>>>(src, dst, rank, E, row_ptr, dinv, edges);

    gemm_kernel<128, 64, 64, 32, true><<<(n + 63) / 64, 256, 0, stream>>>(x, W1, bufAh, n);
    gather64_fuse_kernel<<<(n + 15) / 16, 256, 0, stream>>>(
        bufAh, row_ptr, edges, dinv, b1, W2, bufB, n);
    gather32_final_kernel<<<(n + 15) / 16, 256, 0, stream>>>(
        bufB, row_ptr, edges, dinv, b2, aw, ab, out, n);
}

// Round 9
// 235.733 us; speedup vs baseline: 1.0627x; 1.0070x over previous
//
#include <hip/hip_runtime.h>
#include <hip/hip_fp16.h>
#include <math.h>

#define N_NODES 50000
#define SLICE_SZ 6250          // N_NODES / 8 XCDs

__device__ __forceinline__ void fma4(float4& a, float w, const float4& v) {
    a.x += w * v.x; a.y += w * v.y; a.z += w * v.z; a.w += w * v.w;
}

struct h2x4 { __half2 a, b, c, d; };   // 16 bytes = 8 halves

// ---------------- degree histogram + per-edge rank ----------------
__global__ void count_kernel(const int* __restrict__ dst, int E,
                             int* __restrict__ counts, int* __restrict__ rank) {
    int i = blockIdx.x * blockDim.x + threadIdx.x;
    if (i < E) rank[i] = atomicAdd(&counts[dst[i]], 1);
}

// ---------------- block-level exclusive scan ----------------
__global__ void scan_block_kernel(const int* __restrict__ in, int n,
                                  int* __restrict__ outEx, int* __restrict__ blocksum) {
    __shared__ int s[256];
    int t = threadIdx.x, i = blockIdx.x * 256 + t;
    int v = (i < n) ? in[i] : 0;
    s[t] = v;
    __syncthreads();
    for (int off = 1; off < 256; off <<= 1) {
        int x = (t >= off) ? s[t - off] : 0;
        __syncthreads();
        s[t] += x;
        __syncthreads();
    }
    if (i < n) outEx[i] = s[t] - v;
    if (t == 255 && blocksum) blocksum[blockIdx.x] = s[255];
}

__global__ void finalize_kernel(const int* __restrict__ counts, const int* __restrict__ blocksum,
                                int n, int E, int* __restrict__ row_ptr,
                                float* __restrict__ dinv) {
    int i = blockIdx.x * blockDim.x + threadIdx.x;
    if (i < n) {
        row_ptr[i] += blocksum[i >> 8];
        dinv[i] = rsqrtf((float)(counts[i] + 1));   // +1 self-loop
        if (i == 0) row_ptr[n] = E;
    }
}

// ---------------- XCD-sliced, atomic-free CSR fill ----------------
__global__ void fill2_kernel(const int* __restrict__ src, const int* __restrict__ dst,
                             const int* __restrict__ rank, int E,
                             const int* __restrict__ row_ptr, const float* __restrict__ dinv,
                             int2* __restrict__ edges) {
    const int slice = blockIdx.x & 7;
    const int chunk = blockIdx.x >> 3;
    const int CS = (((E + 255) >> 8) + 3) & ~3;      // chunk size, multiple of 4
    const int lo = chunk * CS;
    const int hi = min(E, lo + CS);
    const int slo = slice * SLICE_SZ, shi = slo + SLICE_SZ;
    if (lo >= E) return;
    const int quad_end = lo + ((hi - lo) & ~3);
    for (int i = lo + threadIdx.x * 4; i + 3 < quad_end + 4 && i + 3 < hi + 4 && i < quad_end; i += 1024) {
        int4 d4 = *(const int4*)&dst[i];
        #pragma unroll
        for (int k = 0; k < 4; ++k) {
            int d = (&d4.x)[k];
            if (d >= slo && d < shi) {
                int s = src[i + k];
                int p = row_ptr[d] + rank[i + k];
                edges[p] = make_int2(s, __float_as_int(dinv[s] * dinv[d]));
            }
        }
    }
    for (int i = quad_end + threadIdx.x; i < hi; i += 256) {   // scalar tail
        int d = dst[i];
        if (d >= slo && d < shi) {
            int s = src[i];
            int p = row_ptr[d] + rank[i];
            edges[p] = make_int2(s, __float_as_int(dinv[s] * dinv[d]));
        }
    }
}

// ---------------- fp32 GEMM: C[n,DOUT] = A[n,DIN] @ W[DIN,DOUT] ----------------
template<int DIN, int DOUT, int BM, int KC, bool HOUT>
__global__ __launch_bounds__(256, 2) void gemm_kernel(const float* __restrict__ A,
                                                      const float* __restrict__ W,
                                                      void* __restrict__ Cv, int n) {
    constexpr int NCG = DOUT / 4;
    constexpr int NRG = BM / 4;
    static_assert(NCG * NRG == 256, "thread mapping");
    constexpr int KG = KC / 4;
    constexpr int RSTEP = 256 / KG;
    __shared__ __align__(16) float ws[DIN * DOUT];
    __shared__ __align__(16) float xs[KC][BM + 4];
    const int t = threadIdx.x;
    for (int i = 4 * t; i < DIN * DOUT; i += 1024)
        *(float4*)&ws[i] = *(const float4*)&W[i];
    const int rowbase = blockIdx.x * BM;
    const int r0 = (t / NCG) * 4;
    const int c0 = (t % NCG) * 4;
    const int lk = (t % KG) * 4;
    const int lr = t / KG;
    float acc[4][4] = {};
    for (int kc = 0; kc < DIN; kc += KC) {
        __syncthreads();
        #pragma unroll
        for (int r = lr; r < BM; r += RSTEP) {
            int row = rowbase + r;
            if (row >= n) row = n - 1;
            float4 v = *(const float4*)&A[(size_t)row * DIN + kc + lk];
            xs[lk + 0][r] = v.x; xs[lk + 1][r] = v.y;
            xs[lk + 2][r] = v.z; xs[lk + 3][r] = v.w;
        }
        __syncthreads();
        #pragma unroll 8
        for (int k = 0; k < KC; ++k) {
            float ar[4], wr[4];
            *(float4*)ar = *(const float4*)&xs[k][r0];
            *(float4*)wr = *(const float4*)&ws[(kc + k) * DOUT + c0];
            #pragma unroll
            for (int i = 0; i < 4; ++i)
                #pragma unroll
                for (int j = 0; j < 4; ++j)
                    acc[i][j] += ar[i] * wr[j];
        }
    }
    #pragma unroll
    for (int i = 0; i < 4; ++i) {
        int row = rowbase + r0 + i;
        if (row < n) {
            if constexpr (HOUT) {
                union { uint2 u; __half2 h[2]; } pk;
                pk.h[0] = __floats2half2_rn(acc[i][0], acc[i][1]);
                pk.h[1] = __floats2half2_rn(acc[i][2], acc[i][3]);
                *(uint2*)((__half*)Cv + (size_t)row * DOUT + c0) = pk.u;
            } else {
                float4 v = make_float4(acc[i][0], acc[i][1], acc[i][2], acc[i][3]);
                *(float4*)&((float*)Cv)[(size_t)row * DOUT + c0] = v;
            }
        }
    }
}

// ---------------- layer-1 gather (8 lanes x 16B per row) + fused GEMM2 ----------------
// Wave per node-quad. Lanes = 8 fg (16B = 8 halves) x 8 ways.
// One wave-instruction now covers 8 edges (vs 4): divergent-vmem instr count
// and lane-address count per edge both halve -- the measured bottleneck.
__global__ __launch_bounds__(256) void gather64_fuse_kernel(
        const __half* __restrict__ XWh, const int* __restrict__ row_ptr,
        const int2* __restrict__ edges, const float* __restrict__ dinv,
        const float* __restrict__ b1, const float* __restrict__ W2,
        float* __restrict__ out, int n) {
    __shared__ float ws2[64 * 33];     // plain row pad 33: epilogue is 2-way aliased (free)
    const int t = threadIdx.x;
    for (int i = t; i < 64 * 32; i += 256) {
        int f = i >> 5, j = i & 31;
        ws2[f * 33 + j] = W2[i];
    }
    __syncthreads();
    const int lane = t & 63;
    const int wid = t >> 6;
    const int fg = lane & 7, way = lane >> 3;
    const h2x4* __restrict__ XW16 = (const h2x4*)XWh;   // 8 units of 16B per row
    for (int it = 0; it < 4; ++it) {
        const int node = blockIdx.x * 16 + wid * 4 + it;
        if (node >= n) break;                       // wave-uniform
        const int start = row_ptr[node];
        const int deg = row_ptr[node + 1] - start;
        const int K = deg + 1;                      // + self record
        // phase A: lane k holds record k (k=0: self; pad = weight-0 self)
        int2 rec;
        if (lane == 0) {
            float dv = dinv[node];
            rec = make_int2(node, __float_as_int(dv * dv));
        } else if (lane <= deg) {
            rec = edges[start + lane - 1];
        } else {
            rec = make_int2(node, 0);
        }
        float4 a0 = make_float4(0.f, 0.f, 0.f, 0.f);
        float4 a1 = make_float4(0.f, 0.f, 0.f, 0.f);
        const int KP = (min(K, 64) + 7) & ~7;       // uniform per-way count
        int k = way;
        #define G64_STEP(kk)                                                   \
            { int sv = __shfl(rec.x, (kk), 64);                                \
              float wgt = __int_as_float(__shfl(rec.y, (kk), 64));             \
              h2x4 rr = XW16[(size_t)sv * 8 + fg];                             \
              float2 f0 = __half22float2(rr.a), f1 = __half22float2(rr.b);     \
              float2 f2 = __half22float2(rr.c), f3 = __half22float2(rr.d);     \
              a0.x += wgt * f0.x; a0.y += wgt * f0.y;                          \
              a0.z += wgt * f1.x; a0.w += wgt * f1.y;                          \
              a1.x += wgt * f2.x; a1.y += wgt * f2.y;                          \
              a1.z += wgt * f3.x; a1.w += wgt * f3.y; }
        for (; k + 8 < KP; k += 16) { G64_STEP(k) G64_STEP(k + 8) }
        for (; k < KP; k += 8) G64_STEP(k)
        #undef G64_STEP
        for (int kk = 64 + way; kk < K; kk += 8) {  // deg>63: direct (never in practice)
            int2 p = edges[start + kk - 1];
            float wgt = __int_as_float(p.y);
            h2x4 rr = XW16[(size_t)p.x * 8 + fg];
            float2 f0 = __half22float2(rr.a), f1 = __half22float2(rr.b);
            float2 f2 = __half22float2(rr.c), f3 = __half22float2(rr.d);
            a0.x += wgt * f0.x; a0.y += wgt * f0.y;
            a0.z += wgt * f1.x; a0.w += wgt * f1.y;
            a1.x += wgt * f2.x; a1.y += wgt * f2.y;
            a1.z += wgt * f3.x; a1.w += wgt * f3.y;
        }
        // reduce across the 8 ways (lane bits 3,4,5)
        #pragma unroll
        for (int m = 8; m <= 32; m <<= 1) {
            a0.x += __shfl_xor(a0.x, m, 64);
            a0.y += __shfl_xor(a0.y, m, 64);
            a0.z += __shfl_xor(a0.z, m, 64);
            a0.w += __shfl_xor(a0.w, m, 64);
            a1.x += __shfl_xor(a1.x, m, 64);
            a1.y += __shfl_xor(a1.y, m, 64);
            a1.z += __shfl_xor(a1.z, m, 64);
            a1.w += __shfl_xor(a1.w, m, 64);
        }
        float4 bA = ((const float4*)b1)[2 * fg];
        float4 bB = ((const float4*)b1)[2 * fg + 1];
        float4 h0, h1;
        h0.x = fmaxf(a0.x + bA.x, 0.f); h0.y = fmaxf(a0.y + bA.y, 0.f);
        h0.z = fmaxf(a0.z + bA.z, 0.f); h0.w = fmaxf(a0.w + bA.w, 0.f);
        h1.x = fmaxf(a1.x + bB.x, 0.f); h1.y = fmaxf(a1.y + bB.y, 0.f);
        h1.z = fmaxf(a1.z + bB.z, 0.f); h1.w = fmaxf(a1.w + bB.w, 0.f);
        // fused GEMM2: lane (fg,way) -> cols [4*way,4*way+4) over feats [8*fg,8*fg+8)
        float py[4];
        #pragma unroll
        for (int s = 0; s < 4; ++s) {
            const float* col = &ws2[(8 * fg) * 33 + 4 * way + s];
            py[s] = h0.x * col[0]   + h0.y * col[33]  + h0.z * col[66]  + h0.w * col[99]
                  + h1.x * col[132] + h1.y * col[165] + h1.z * col[198] + h1.w * col[231];
        }
        #pragma unroll
        for (int m = 1; m <= 4; m <<= 1) {
            #pragma unroll
            for (int s = 0; s < 4; ++s) py[s] += __shfl_xor(py[s], m, 64);
        }
        if (fg == 0)
            *(float4*)&out[(size_t)node * 32 + 4 * way] =
                make_float4(py[0], py[1], py[2], py[3]);
    }
}

// ---------------- layer-2 gather (shfl-broadcast) + attention epilogue ----------------
// Wave per node-quad. Lanes = 8 fg (float4) x 8 ways. (Already 8 lanes/row.)
__global__ __launch_bounds__(256) void gather32_final_kernel(
        const float* __restrict__ XW, const int* __restrict__ row_ptr,
        const int2* __restrict__ edges, const float* __restrict__ dinv,
        const float* __restrict__ b2, const float* __restrict__ aw,
        const float* __restrict__ ab, float* __restrict__ out, int n) {
    const int t = threadIdx.x;
    const int lane = t & 63;
    const int wid = t >> 6;
    const int fg = lane & 7, way = lane >> 3;
    const float4* __restrict__ XW4 = (const float4*)XW;
    for (int it = 0; it < 4; ++it) {
        const int node = blockIdx.x * 16 + wid * 4 + it;
        if (node >= n) break;
        const int start = row_ptr[node];
        const int deg = row_ptr[node + 1] - start;
        const int K = deg + 1;
        int2 rec;
        if (lane == 0) {
            float dv = dinv[node];
            rec = make_int2(node, __float_as_int(dv * dv));
        } else if (lane <= deg) {
            rec = edges[start + lane - 1];
        } else {
            rec = make_int2(node, 0);
        }
        float4 acc = make_float4(0.f, 0.f, 0.f, 0.f);
        const int KP = (min(K, 64) + 7) & ~7;
        int k = way;
        #define G32_STEP(kk)                                                   \
            { int sv = __shfl(rec.x, (kk), 64);                                \
              float wgt = __int_as_float(__shfl(rec.y, (kk), 64));             \
              float4 v = XW4[(size_t)sv * 8 + fg];                             \
              fma4(acc, wgt, v); }
        for (; k + 8 < KP; k += 16) { G32_STEP(k) G32_STEP(k + 8) }
        for (; k < KP; k += 8) G32_STEP(k)
        #undef G32_STEP
        for (int kk = 64 + way; kk < K; kk += 8) {  // deg>63: direct (never in practice)
            int2 p = edges[start + kk - 1];
            fma4(acc, __int_as_float(p.y), XW4[(size_t)p.x * 8 + fg]);
        }
        #pragma unroll
        for (int m = 8; m <= 32; m <<= 1) {
            acc.x += __shfl_xor(acc.x, m, 64);
            acc.y += __shfl_xor(acc.y, m, 64);
            acc.z += __shfl_xor(acc.z, m, 64);
            acc.w += __shfl_xor(acc.w, m, 64);
        }
        float4 b = ((const float4*)b2)[fg];
        float4 h;
        h.x = fmaxf(acc.x + b.x, 0.f);
        h.y = fmaxf(acc.y + b.y, 0.f);
        h.z = fmaxf(acc.z + b.z, 0.f);
        h.w = fmaxf(acc.w + b.w, 0.f);
        float4 a4 = ((const float4*)aw)[fg];
        float sca = h.x * a4.x + h.y * a4.y + h.z * a4.z + h.w * a4.w;
        sca += __shfl_xor(sca, 1, 64);
        sca += __shfl_xor(sca, 2, 64);
        sca += __shfl_xor(sca, 4, 64);
        float attn = 1.f / (1.f + __expf(-(sca + ab[0])));
        if (way == 0) {
            float4 r = make_float4(h.x * attn, h.y * attn, h.z * attn, h.w * attn);
            ((float4*)&out[(size_t)node * 32])[fg] = r;
        }
    }
}

extern "C" void kernel_launch(void* const* d_in, const int* in_sizes, int n_in,
                              void* d_out, int out_size, void* d_ws, size_t ws_size,
                              hipStream_t stream) {
    const float* x  = (const float*)d_in[0];
    const int*   ei = (const int*)d_in[1];
    const float* W1 = (const float*)d_in[2];
    const float* b1 = (const float*)d_in[3];
    const float* W2 = (const float*)d_in[4];
    const float* b2 = (const float*)d_in[5];
    const float* aw = (const float*)d_in[6];
    const float* ab = (const float*)d_in[7];
    float* out = (float*)d_out;

    const int n = N_NODES;
    const int E = in_sizes[1] / 2;
    const int* src = ei;
    const int* dst = ei + E;

    char* w = (char*)d_ws;
    auto alloc = [&](size_t bytes) { char* p = w; w += (bytes + 255) & ~(size_t)255; return p; };
    int*    counts   = (int*)   alloc((size_t)n * 4);
    int*    row_ptr  = (int*)   alloc((size_t)(n + 1) * 4);
    int*    rank     = (int*)   alloc((size_t)E * 4);
    int*    blocksum = (int*)   alloc(1024);
    float*  dinv     = (float*) alloc((size_t)n * 4);
    int2*   edges    = (int2*)  alloc((size_t)E * 8);
    __half* bufAh    = (__half*)alloc((size_t)n * 64 * 2);   // XW1 (fp16 table)
    float*  bufB     = (float*) alloc((size_t)n * 32 * 4);   // XW2 (fp32)

    const int nb = (n + 255) / 256;

    hipMemsetAsync(counts, 0, (size_t)n * 4, stream);
    count_kernel<<<(E + 255) / 256, 256, 0, stream>>>(dst, E, counts, rank);
    scan_block_kernel<<<nb, 256, 0, stream>>>(counts, n, row_ptr, blocksum);
    scan_block_kernel<<<1, 256, 0, stream>>>(blocksum, nb, blocksum, nullptr);
    finalize_kernel<<<nb, 256, 0, stream>>>(counts, blocksum, n, E, row_ptr, dinv);
    fill2_kernel<<<256 * 8, 256, 0, stream>>>(src, dst, rank, E, row_ptr, dinv, edges);

    gemm_kernel<128, 64, 64, 32, true><<<(n + 63) / 64, 256, 0, stream>>>(x, W1, bufAh, n);
    gather64_fuse_kernel<<<(n + 15) / 16, 256, 0, stream>>>(
        bufAh, row_ptr, edges, dinv, b1, W2, bufB, n);
    gather32_final_kernel<<<(n + 15) / 16, 256, 0, stream>>>(
        bufB, row_ptr, edges, dinv, b2, aw, ab, out, n);
}